// Round 8
// baseline (234.555 us; speedup 1.0000x reference)
//
#include <hip/hip_runtime.h>
#include <cstdint>
#include <cstddef>

typedef __bf16 bf16_t;
typedef bf16_t bf16x8 __attribute__((ext_vector_type(8)));
typedef bf16_t bf16x4 __attribute__((ext_vector_type(4)));
typedef float f32x4 __attribute__((ext_vector_type(4)));

__device__ __forceinline__ void gl_lds16(const void* g, void* l) {
  __builtin_amdgcn_global_load_lds(
      (const __attribute__((address_space(1))) void*)g,
      (__attribute__((address_space(3))) void*)l, 16, 0, 0);
}

__device__ __forceinline__ f32x4 mfma16(bf16x8 a, bf16x8 b, f32x4 c) {
  return __builtin_amdgcn_mfma_f32_16x16x32_bf16(a, b, c, 0, 0, 0);
}

// ---------------- weights fp32 -> bf16 (Wo, Wv, Wk, Wq; 1,048,576 elems each) ----
struct CvtWArgs { const float* src[4]; };

__global__ __launch_bounds__(256) void convert_w(CvtWArgs a, bf16_t* __restrict__ dst) {
  unsigned g = blockIdx.x * 256u + threadIdx.x;   // 524,288 groups of 8
  unsigned seg = g >> 17, off = g & 0x1FFFFu;
  const float4* s = (const float4*)a.src[seg] + (size_t)off * 2;
  float4 x0 = s[0], x1 = s[1];
  bf16x8 o;
  o[0] = (bf16_t)x0.x; o[1] = (bf16_t)x0.y; o[2] = (bf16_t)x0.z; o[3] = (bf16_t)x0.w;
  o[4] = (bf16_t)x1.x; o[5] = (bf16_t)x1.y; o[6] = (bf16_t)x1.z; o[7] = (bf16_t)x1.w;
  *(bf16x8*)(dst + (size_t)g * 8) = o;
}

// ---------------- fused QKV projection (A fp32, W bf16, out bf16) ----------------
// Double-buffered single-barrier K-loop: iter k prefetches A(k+1) (fp32, cvt at
// write) and W(k+1) (uint4) into REGISTERS, computes from buf[k&1], stores into
// buf[~k&1], one __syncthreads per iter. Global-load latency hidden by compute.
// z=0: V -> vt [bh][e][s_perm]; z=1: K -> [bh][s][e]; z=2: Q -> [bh][s][e]*0.125
struct ProjArgs {
  const float* A[3]; const bf16_t* W[3]; const float* bias[3];
  bf16_t* out[3]; float scale[3];
};

__global__ __launch_bounds__(256, 2) void gemm_proj(ProjArgs p) {
  __shared__ __attribute__((aligned(16))) unsigned char smem[65536];
  bf16_t* a_buf = (bf16_t*)smem;              // 2 x (128x64 bf16, 16 KB)
  bf16_t* b_buf = (bf16_t*)(smem + 32768);    // 2 x (128x64 bf16, 16 KB)
  const int K = 1024;
  const int z = blockIdx.z;
  const float*  A = p.A[z] + (size_t)blockIdx.x * 128 * K;
  const bf16_t* W = p.W[z] + (size_t)blockIdx.y * 128 * K;

  const int t = threadIdx.x;
  const int l = t & 63;
  const int lq = l >> 4, lr = l & 15;
  const int w = t >> 6;
  const int mq = w & 1, nq = w >> 1;

  // staging address components
  const int ar[8] = { (t + 0*256) >> 4, (t + 1*256) >> 4, (t + 2*256) >> 4, (t + 3*256) >> 4,
                      (t + 4*256) >> 4, (t + 5*256) >> 4, (t + 6*256) >> 4, (t + 7*256) >> 4 };
  const int ac16 = t & 15;                    // same for all f (c16 = g&15, g=t+f*256)
  f32x4 acc[4][4];
  f32x4 zero = {0.f, 0.f, 0.f, 0.f};
  #pragma unroll
  for (int i = 0; i < 4; i++)
    #pragma unroll
    for (int j = 0; j < 4; j++) acc[i][j] = zero;

  // ---- prologue: stage tile 0 into buf 0 ----
  {
    float4 av[8]; uint4 wv[4];
    #pragma unroll
    for (int f = 0; f < 8; f++)
      av[f] = *(const float4*)(A + (size_t)ar[f] * K + ac16 * 4);
    #pragma unroll
    for (int i = 0; i < 4; i++) {
      int g = t + i * 256, r = g >> 3, pc = g & 7, lc = pc ^ (r & 7);
      wv[i] = *(const uint4*)(W + (size_t)r * K + lc * 8);
    }
    #pragma unroll
    for (int f = 0; f < 8; f++) {
      int r = ar[f];
      int phys = (ac16 >> 1) ^ (r & 7);
      bf16x4 bv;
      bv[0] = (bf16_t)av[f].x; bv[1] = (bf16_t)av[f].y;
      bv[2] = (bf16_t)av[f].z; bv[3] = (bf16_t)av[f].w;
      *(bf16x4*)(a_buf + r * 64 + phys * 8 + (ac16 & 1) * 4) = bv;
    }
    #pragma unroll
    for (int i = 0; i < 4; i++) {
      int g = t + i * 256;
      *(uint4*)(b_buf + g * 8) = wv[i];
    }
  }

  for (int kt = 0; kt < 16; ++kt) {
    __syncthreads();                          // buf[kt&1] ready; prev reads done
    bf16_t* acur = a_buf + (kt & 1) * 8192;
    bf16_t* bcur = b_buf + (kt & 1) * 8192;

    float4 av[8]; uint4 wv[4];
    if (kt < 15) {                            // prefetch next tile into regs
      int k0 = (kt + 1) * 64;
      #pragma unroll
      for (int f = 0; f < 8; f++)
        av[f] = *(const float4*)(A + (size_t)ar[f] * K + k0 + ac16 * 4);
      #pragma unroll
      for (int i = 0; i < 4; i++) {
        int g = t + i * 256, r = g >> 3, pc = g & 7, lc = pc ^ (r & 7);
        wv[i] = *(const uint4*)(W + (size_t)r * K + k0 + lc * 8);
      }
    }

    #pragma unroll
    for (int kk = 0; kk < 2; kk++) {
      bf16x8 af[4], bfr[4];
      #pragma unroll
      for (int i = 0; i < 4; i++) {
        int R = mq * 64 + i * 16 + lr;
        int ch = (kk * 4 + lq) ^ (R & 7);
        af[i] = *(const bf16x8*)(acur + R * 64 + ch * 8);
      }
      #pragma unroll
      for (int j = 0; j < 4; j++) {
        int R = nq * 64 + j * 16 + lr;
        int ch = (kk * 4 + lq) ^ (R & 7);
        bfr[j] = *(const bf16x8*)(bcur + R * 64 + ch * 8);
      }
      #pragma unroll
      for (int i = 0; i < 4; i++)
        #pragma unroll
        for (int j = 0; j < 4; j++)
          acc[i][j] = mfma16(af[i], bfr[j], acc[i][j]);
    }

    if (kt < 15) {                            // store prefetched tile to other buf
      bf16_t* anx = a_buf + ((kt + 1) & 1) * 8192;
      bf16_t* bnx = b_buf + ((kt + 1) & 1) * 8192;
      #pragma unroll
      for (int f = 0; f < 8; f++) {
        int r = ar[f];
        int phys = (ac16 >> 1) ^ (r & 7);
        bf16x4 bv;
        bv[0] = (bf16_t)av[f].x; bv[1] = (bf16_t)av[f].y;
        bv[2] = (bf16_t)av[f].z; bv[3] = (bf16_t)av[f].w;
        *(bf16x4*)(anx + r * 64 + phys * 8 + (ac16 & 1) * 4) = bv;
      }
      #pragma unroll
      for (int i = 0; i < 4; i++) {
        int g = t + i * 256;
        *(uint4*)(bnx + g * 8) = wv[i];
      }
    }
  }

  const float* bias = p.bias[z];
  const float scale = p.scale[z];
  __syncthreads();
  bf16_t* ts = (bf16_t*)smem;  // 128 x 136 bf16 = 34,816 B
  #pragma unroll
  for (int i = 0; i < 4; i++) {
    #pragma unroll
    for (int j = 0; j < 4; j++) {
      int nl = nq * 64 + j * 16 + lr;
      float bz = bias[blockIdx.y * 128 + nl];
      #pragma unroll
      for (int r = 0; r < 4; r++) {
        int ml = mq * 64 + i * 16 + lq * 4 + r;
        bf16_t val = (bf16_t)((acc[i][j][r] + bz) * scale);
        if (z == 0) {
          // permute s within its 64-group to PV-fragment order
          int mlp = (ml & 96) | (((ml >> 2) & 3) << 3) | (((ml >> 4) & 1) << 2) | (ml & 3);
          ts[nl * 136 + mlp] = val;   // transposed (+permuted) for vt
        } else {
          ts[ml * 136 + nl] = val;
        }
      }
    }
  }
  __syncthreads();
  bf16_t* out = p.out[z];
  const int b = blockIdx.x >> 4, sbase = (blockIdx.x & 15) * 128;
  if (z == 0) {
    #pragma unroll
    for (int ii = 0; ii < 8; ii++) {
      int idx = t * 8 + ii * 2048;
      int rr = idx >> 7, cc = idx & 127;
      int n = blockIdx.y * 128 + rr;
      int h = n >> 6, e = n & 63;
      bf16x8 vq = *(const bf16x8*)(ts + rr * 136 + cc);
      *(bf16x8*)(out + ((size_t)(b * 16 + h) * 64 + e) * 2048 + sbase + cc) = vq;
    }
  } else {
    #pragma unroll
    for (int ii = 0; ii < 8; ii++) {
      int idx = t * 8 + ii * 2048;
      int rr = idx >> 7, cc = idx & 127;
      int n = blockIdx.y * 128 + cc;
      int h = n >> 6, e = n & 63;
      bf16x8 vq = *(const bf16x8*)(ts + rr * 136 + cc);
      *(bf16x8*)(out + ((size_t)(b * 16 + h) * 2048 + sbase + rr) * 64 + e) = vq;
    }
  }
}

// ---------------- flash attention, S^T formulation (unchanged) ----------------
__global__ __launch_bounds__(256, 4) void attn(
    const bf16_t* __restrict__ qw, const bf16_t* __restrict__ kw,
    const bf16_t* __restrict__ vtw, bf16_t* __restrict__ att)
{
  __shared__ bf16_t k_s[64 * 64];
  __shared__ bf16_t v_s[64 * 64];
  __shared__ bf16_t qe_s[64 * 72];
  const int bh = blockIdx.x, qt = blockIdx.y;
  const int t = threadIdx.x, w = t >> 6, l = t & 63, lq = l >> 4, lr = l & 15;

  const bf16_t* qbase = qw + ((size_t)bh * 2048 + qt * 64) * 64;
  #pragma unroll
  for (int i = 0; i < 2; i++) {
    int g = t + i * 256;
    int r = g >> 3, pc = g & 7;
    int lc = pc ^ (r & 7);
    gl_lds16(qbase + (size_t)r * 64 + lc * 8, qe_s + i * 2048 + w * 512);
  }
  __syncthreads();
  bf16x8 qf[2];
  #pragma unroll
  for (int kk = 0; kk < 2; kk++) {
    int R = w * 16 + lr;
    int ch = (kk * 4 + lq) ^ (R & 7);
    qf[kk] = *(const bf16x8*)(qe_s + R * 64 + ch * 8);
  }

  f32x4 O[4];
  f32x4 zero = {0.f, 0.f, 0.f, 0.f};
  #pragma unroll
  for (int et = 0; et < 4; et++) O[et] = zero;
  float lsum = 0.f;

  for (int kt = 0; kt < 32; ++kt) {
    __syncthreads();
    const bf16_t* kbase = kw + ((size_t)bh * 2048 + kt * 64) * 64;
    const bf16_t* vbase = vtw + (size_t)bh * 131072 + (size_t)kt * 64;
    #pragma unroll
    for (int i = 0; i < 2; i++) {
      int g = t + i * 256;
      int r = g >> 3, pc = g & 7;
      int lc = pc ^ (r & 7);
      gl_lds16(kbase + (size_t)r * 64 + lc * 8, k_s + i * 2048 + w * 512);
      gl_lds16(vbase + (size_t)r * 2048 + lc * 8, v_s + i * 2048 + w * 512);
    }
    __syncthreads();

    f32x4 sc[4];
    #pragma unroll
    for (int j = 0; j < 4; j++) sc[j] = zero;
    #pragma unroll
    for (int kk = 0; kk < 2; kk++) {
      #pragma unroll
      for (int j = 0; j < 4; j++) {
        int R = j * 16 + lr;
        int ch = (kk * 4 + lq) ^ (R & 7);
        bf16x8 kf = *(const bf16x8*)(k_s + R * 64 + ch * 8);
        sc[j] = mfma16(kf, qf[kk], sc[j]);   // D[key][q]
      }
    }

    bf16x8 pb[2];
    #pragma unroll
    for (int ks2 = 0; ks2 < 2; ks2++) {
      #pragma unroll
      for (int r = 0; r < 4; r++) {
        float e0 = __expf(sc[2 * ks2][r]);
        float e1 = __expf(sc[2 * ks2 + 1][r]);
        lsum += e0 + e1;
        pb[ks2][r] = (bf16_t)e0;
        pb[ks2][4 + r] = (bf16_t)e1;
      }
    }

    #pragma unroll
    for (int ks2 = 0; ks2 < 2; ks2++) {
      #pragma unroll
      for (int et = 0; et < 4; et++) {
        int R = et * 16 + lr;
        int ch = (ks2 * 4 + lq) ^ (R & 7);
        bf16x8 vf = *(const bf16x8*)(v_s + R * 64 + ch * 8);
        O[et] = mfma16(vf, pb[ks2], O[et]);
      }
    }
  }

  float s = lsum;
  s += __shfl_xor(s, 16);
  s += __shfl_xor(s, 32);
  float rinv = 1.0f / s;

  #pragma unroll
  for (int et = 0; et < 4; et++) {
    bf16x4 pv;
    #pragma unroll
    for (int r = 0; r < 4; r++) pv[r] = (bf16_t)(O[et][r] * rinv);
    *(bf16x4*)(qe_s + (w * 16 + lr) * 72 + et * 16 + lq * 4) = pv;
  }
  __syncthreads();
  const int b = bh >> 4, h = bh & 15;
  #pragma unroll
  for (int i = 0; i < 2; i++) {
    int c = t + i * 256;
    int row = c >> 3, c8 = c & 7;
    bf16x8 vv = *(const bf16x8*)(qe_s + row * 72 + c8 * 8);
    *(bf16x8*)(att + ((size_t)b * 2048 + qt * 64 + row) * 1024 + h * 64 + c8 * 8) = vv;
  }
}

// ---------------- output projection (A bf16, W bf16, out fp32) ----------------
// Same single-barrier dbuf structure; 64x128 tile, grid (64, 8).
__global__ __launch_bounds__(256, 2) void gemm_out(
    const bf16_t* __restrict__ A, const bf16_t* __restrict__ W,
    const float* __restrict__ bias, float* __restrict__ out)
{
  __shared__ __attribute__((aligned(16))) unsigned char smem[49152];
  bf16_t* a_buf = (bf16_t*)smem;              // 2 x (64x64 bf16, 8 KB)
  bf16_t* b_buf = (bf16_t*)(smem + 16384);    // 2 x (128x64 bf16, 16 KB)
  const int K = 1024;
  const bf16_t* Ab = A + (size_t)blockIdx.x * 64 * K;
  const bf16_t* Wb = W + (size_t)blockIdx.y * 128 * K;
  const int t = threadIdx.x, w = t >> 6, l = t & 63, lq = l >> 4, lr = l & 15;
  const int mh = w & 1, nh = w >> 1;

  f32x4 acc[2][4];
  f32x4 zero = {0.f, 0.f, 0.f, 0.f};
  #pragma unroll
  for (int i = 0; i < 2; i++)
    #pragma unroll
    for (int j = 0; j < 4; j++) acc[i][j] = zero;

  {
    uint4 avv[2], wv[4];
    #pragma unroll
    for (int i = 0; i < 2; i++) {
      int g = t + i * 256, r = g >> 3, pc = g & 7, lc = pc ^ (r & 7);
      avv[i] = *(const uint4*)(Ab + (size_t)r * K + lc * 8);
    }
    #pragma unroll
    for (int i = 0; i < 4; i++) {
      int g = t + i * 256, r = g >> 3, pc = g & 7, lc = pc ^ (r & 7);
      wv[i] = *(const uint4*)(Wb + (size_t)r * K + lc * 8);
    }
    #pragma unroll
    for (int i = 0; i < 2; i++) { int g = t + i * 256; *(uint4*)(a_buf + g * 8) = avv[i]; }
    #pragma unroll
    for (int i = 0; i < 4; i++) { int g = t + i * 256; *(uint4*)(b_buf + g * 8) = wv[i]; }
  }

  for (int kt = 0; kt < 16; ++kt) {
    __syncthreads();
    bf16_t* acur = a_buf + (kt & 1) * 4096;
    bf16_t* bcur = b_buf + (kt & 1) * 8192;

    uint4 avv[2], wv[4];
    if (kt < 15) {
      int k0 = (kt + 1) * 64;
      #pragma unroll
      for (int i = 0; i < 2; i++) {
        int g = t + i * 256, r = g >> 3, pc = g & 7, lc = pc ^ (r & 7);
        avv[i] = *(const uint4*)(Ab + (size_t)r * K + k0 + lc * 8);
      }
      #pragma unroll
      for (int i = 0; i < 4; i++) {
        int g = t + i * 256, r = g >> 3, pc = g & 7, lc = pc ^ (r & 7);
        wv[i] = *(const uint4*)(Wb + (size_t)r * K + k0 + lc * 8);
      }
    }

    #pragma unroll
    for (int kk = 0; kk < 2; kk++) {
      bf16x8 af[2], bfr[4];
      #pragma unroll
      for (int i = 0; i < 2; i++) {
        int R = mh * 32 + i * 16 + lr;
        int ch = (kk * 4 + lq) ^ (R & 7);
        af[i] = *(const bf16x8*)(acur + R * 64 + ch * 8);
      }
      #pragma unroll
      for (int j = 0; j < 4; j++) {
        int R = nh * 64 + j * 16 + lr;
        int ch = (kk * 4 + lq) ^ (R & 7);
        bfr[j] = *(const bf16x8*)(bcur + R * 64 + ch * 8);
      }
      #pragma unroll
      for (int i = 0; i < 2; i++)
        #pragma unroll
        for (int j = 0; j < 4; j++)
          acc[i][j] = mfma16(af[i], bfr[j], acc[i][j]);
    }

    if (kt < 15) {
      bf16_t* anx = a_buf + ((kt + 1) & 1) * 4096;
      bf16_t* bnx = b_buf + ((kt + 1) & 1) * 8192;
      #pragma unroll
      for (int i = 0; i < 2; i++) { int g = t + i * 256; *(uint4*)(anx + g * 8) = avv[i]; }
      #pragma unroll
      for (int i = 0; i < 4; i++) { int g = t + i * 256; *(uint4*)(bnx + g * 8) = wv[i]; }
    }
  }

  #pragma unroll
  for (int i = 0; i < 2; i++) {
    #pragma unroll
    for (int j = 0; j < 4; j++) {
      int col = blockIdx.y * 128 + nh * 64 + j * 16 + lr;
      float bz = bias[col];
      #pragma unroll
      for (int r = 0; r < 4; r++) {
        int row = blockIdx.x * 64 + mh * 32 + i * 16 + lq * 4 + r;
        out[(size_t)row * 1024 + col] = acc[i][j][r] + bz;
      }
    }
  }
}

// ---------------- launch ----------------
extern "C" void kernel_launch(void* const* d_in, const int* in_sizes, int n_in,
                              void* d_out, int out_size, void* d_ws, size_t ws_size,
                              hipStream_t stream) {
  (void)in_sizes; (void)n_in; (void)out_size;
  const float* V  = (const float*)d_in[0];
  const float* Kx = (const float*)d_in[1];
  const float* Q  = (const float*)d_in[2];
  const float* Wv = (const float*)d_in[3];
  const float* bv = (const float*)d_in[4];
  const float* Wk = (const float*)d_in[5];
  const float* bk = (const float*)d_in[6];
  const float* Wq = (const float*)d_in[7];
  const float* bq = (const float*)d_in[8];
  const float* Wo = (const float*)d_in[9];
  const float* bo = (const float*)d_in[10];

  const size_t E = 1048576;
  if (ws_size < 20 * E * sizeof(bf16_t)) return;  // 40 MB needed

  bf16_t* ws = (bf16_t*)d_ws;
  bf16_t* cWo   = ws;            // 1E
  bf16_t* cWv   = ws + E;        // 1E
  bf16_t* cWk   = ws + 2 * E;    // 1E
  bf16_t* cWq   = ws + 3 * E;    // 1E
  bf16_t* q_ws  = ws + 4 * E;    // 4E  [bh][s][e], pre-scaled by 0.125
  bf16_t* k_ws  = ws + 8 * E;    // 4E  [bh][s][e]
  bf16_t* vt_ws = ws + 12 * E;   // 4E  [bh][e][s_perm]
  bf16_t* att_ws= ws + 16 * E;   // 4E  [b][s][h*64+e]

  CvtWArgs cw;
  cw.src[0] = Wo; cw.src[1] = Wv; cw.src[2] = Wk; cw.src[3] = Wq;
  convert_w<<<2048, 256, 0, stream>>>(cw, ws);

  ProjArgs pa;
  pa.A[0] = V;   pa.A[1] = Kx;  pa.A[2] = Q;
  pa.W[0] = cWv; pa.W[1] = cWk; pa.W[2] = cWq;
  pa.bias[0] = bv; pa.bias[1] = bk; pa.bias[2] = bq;
  pa.out[0] = vt_ws; pa.out[1] = k_ws; pa.out[2] = q_ws;
  pa.scale[0] = 1.f; pa.scale[1] = 1.f; pa.scale[2] = 0.125f;
  gemm_proj<<<dim3(32, 8, 3), 256, 0, stream>>>(pa);

  attn<<<dim3(32, 32), 256, 0, stream>>>(q_ws, k_ws, vt_ws, att_ws);

  gemm_out<<<dim3(64, 8), 256, 0, stream>>>(att_ws, cWo, bo, (float*)d_out);
}

// Round 10
// 216.169 us; speedup vs baseline: 1.0851x; 1.0851x over previous
//
#include <hip/hip_runtime.h>
#include <cstdint>
#include <cstddef>

typedef __bf16 bf16_t;
typedef bf16_t bf16x8 __attribute__((ext_vector_type(8)));
typedef bf16_t bf16x4 __attribute__((ext_vector_type(4)));
typedef float f32x4 __attribute__((ext_vector_type(4)));

__device__ __forceinline__ void gl_lds16(const void* g, void* l) {
  __builtin_amdgcn_global_load_lds(
      (const __attribute__((address_space(1))) void*)g,
      (__attribute__((address_space(3))) void*)l, 16, 0, 0);
}

__device__ __forceinline__ f32x4 mfma16(bf16x8 a, bf16x8 b, f32x4 c) {
  return __builtin_amdgcn_mfma_f32_16x16x32_bf16(a, b, c, 0, 0, 0);
}

// ---------------- weights fp32 -> bf16 (Wo, Wv, Wk, Wq; 1,048,576 elems each) ----
struct CvtWArgs { const float* src[4]; };

__global__ __launch_bounds__(256) void convert_w(CvtWArgs a, bf16_t* __restrict__ dst) {
  unsigned g = blockIdx.x * 256u + threadIdx.x;   // 524,288 groups of 8
  unsigned seg = g >> 17, off = g & 0x1FFFFu;
  const float4* s = (const float4*)a.src[seg] + (size_t)off * 2;
  float4 x0 = s[0], x1 = s[1];
  bf16x8 o;
  o[0] = (bf16_t)x0.x; o[1] = (bf16_t)x0.y; o[2] = (bf16_t)x0.z; o[3] = (bf16_t)x0.w;
  o[4] = (bf16_t)x1.x; o[5] = (bf16_t)x1.y; o[6] = (bf16_t)x1.z; o[7] = (bf16_t)x1.w;
  *(bf16x8*)(dst + (size_t)g * 8) = o;
}

// ---------------- fused QKV projection (A fp32, W bf16, out bf16) ----------------
// 64x128 tile, grid (64, 8, 3) -> 1536 blocks (~6/CU): latency hiding via many
// independent barrier groups. A staged fp32->bf16 through registers (loads
// hoisted above the barrier); W via LDS-DMA. Single-buffer, 2 barriers/iter.
// z=0: V -> vt [bh][e][s_perm]; z=1: K -> [bh][s][e]; z=2: Q -> [bh][s][e]*0.125
struct ProjArgs {
  const float* A[3]; const bf16_t* W[3]; const float* bias[3];
  bf16_t* out[3]; float scale[3];
};

__global__ __launch_bounds__(256, 5) void gemm_proj(ProjArgs p) {
  __shared__ __attribute__((aligned(16))) unsigned char smem[24576];
  bf16_t* a_s = (bf16_t*)smem;             // 64 x 64 bf16 (8 KB)
  bf16_t* b_s = (bf16_t*)(smem + 8192);    // 128 x 64 bf16 (16 KB)
  const int K = 1024;
  const int z = blockIdx.z;
  const float*  A = p.A[z] + (size_t)blockIdx.x * 64 * K;
  const bf16_t* W = p.W[z] + (size_t)blockIdx.y * 128 * K;

  const int t = threadIdx.x;
  const int l = t & 63;
  const int lq = l >> 4, lr = l & 15;
  const int w = t >> 6;
  const int mh = w & 1, nh = w >> 1;

  const int ar0 = t >> 4, ac16 = t & 15;   // A chunk coords: f-th chunk row = ar0 + f*16
  f32x4 acc[2][4];
  f32x4 zero = {0.f, 0.f, 0.f, 0.f};
  #pragma unroll
  for (int i = 0; i < 2; i++)
    #pragma unroll
    for (int j = 0; j < 4; j++) acc[i][j] = zero;

  for (int kt = 0; kt < 16; ++kt) {
    const int k0 = kt * 64;
    // A: 64x64 fp32, 4 coalesced float4 loads -- issued BEFORE the barrier so
    // their latency overlaps the barrier wait.
    float4 av[4];
    #pragma unroll
    for (int f = 0; f < 4; f++)
      av[f] = *(const float4*)(A + (size_t)(ar0 + f * 16) * K + k0 + ac16 * 4);
    __syncthreads();                        // prev compute's LDS reads retired
    #pragma unroll
    for (int i = 0; i < 4; i++) {           // W: 8192 bf16 via DMA
      int g = t + i * 256;
      int r = g >> 3, pc = g & 7;
      int lc = pc ^ (r & 7);
      gl_lds16(W + (size_t)r * K + k0 + lc * 8, b_s + i * 2048 + w * 512);
    }
    #pragma unroll
    for (int f = 0; f < 4; f++) {           // A: cvt + swizzled bf16 stores
      int r = ar0 + f * 16;
      int phys = (ac16 >> 1) ^ (r & 7);
      bf16x4 bv;
      bv[0] = (bf16_t)av[f].x; bv[1] = (bf16_t)av[f].y;
      bv[2] = (bf16_t)av[f].z; bv[3] = (bf16_t)av[f].w;
      *(bf16x4*)(a_s + r * 64 + phys * 8 + (ac16 & 1) * 4) = bv;
    }
    __syncthreads();                        // tiles visible
    #pragma unroll
    for (int kk = 0; kk < 2; kk++) {
      bf16x8 af[2], bfr[4];
      #pragma unroll
      for (int i = 0; i < 2; i++) {
        int R = mh * 32 + i * 16 + lr;
        int ch = (kk * 4 + lq) ^ (R & 7);
        af[i] = *(const bf16x8*)(a_s + R * 64 + ch * 8);
      }
      #pragma unroll
      for (int j = 0; j < 4; j++) {
        int R = nh * 64 + j * 16 + lr;
        int ch = (kk * 4 + lq) ^ (R & 7);
        bfr[j] = *(const bf16x8*)(b_s + R * 64 + ch * 8);
      }
      #pragma unroll
      for (int i = 0; i < 2; i++)
        #pragma unroll
        for (int j = 0; j < 4; j++)
          acc[i][j] = mfma16(af[i], bfr[j], acc[i][j]);
    }
  }

  const float* bias = p.bias[z];
  const float scale = p.scale[z];
  __syncthreads();
  const int b = blockIdx.x >> 5;            // M-row = bx*64 + ml; batch = M>>11
  const int sbase = (blockIdx.x & 31) * 64; // s-base within the batch
  bf16_t* out = p.out[z];
  if (z == 0) {
    bf16_t* ts = (bf16_t*)smem;             // 128 x 72 bf16 = 18,432 B (row = n)
    #pragma unroll
    for (int i = 0; i < 2; i++) {
      #pragma unroll
      for (int j = 0; j < 4; j++) {
        int nl = nh * 64 + j * 16 + lr;
        float bz = bias[blockIdx.y * 128 + nl];
        #pragma unroll
        for (int r = 0; r < 4; r++) {
          int ml = mh * 32 + i * 16 + lq * 4 + r;     // s within the 64-group
          int mlp = (ml & 32) | (((ml >> 2) & 3) << 3) |
                    (((ml >> 4) & 1) << 2) | (ml & 3); // kappa^-1 perm
          ts[nl * 72 + mlp] = (bf16_t)((acc[i][j][r] + bz) * scale);
        }
      }
    }
    __syncthreads();
    #pragma unroll
    for (int ii = 0; ii < 4; ii++) {
      int idx = t * 8 + ii * 2048;          // 8192 elems
      int rr = idx >> 6, cc = idx & 63;     // rr: n-local, cc: s-local(perm)
      int n = blockIdx.y * 128 + rr;
      int h = n >> 6, e = n & 63;
      bf16x8 vq = *(const bf16x8*)(ts + rr * 72 + cc);
      *(bf16x8*)(out + ((size_t)(b * 16 + h) * 64 + e) * 2048 + sbase + cc) = vq;
    }
  } else {
    bf16_t* ts = (bf16_t*)smem;             // 64 x 136 bf16 = 17,408 B (row = m)
    #pragma unroll
    for (int i = 0; i < 2; i++) {
      #pragma unroll
      for (int j = 0; j < 4; j++) {
        int nl = nh * 64 + j * 16 + lr;
        float bz = bias[blockIdx.y * 128 + nl];
        #pragma unroll
        for (int r = 0; r < 4; r++) {
          int ml = mh * 32 + i * 16 + lq * 4 + r;
          ts[ml * 136 + nl] = (bf16_t)((acc[i][j][r] + bz) * scale);
        }
      }
    }
    __syncthreads();
    #pragma unroll
    for (int ii = 0; ii < 4; ii++) {
      int idx = t * 8 + ii * 2048;
      int rr = idx >> 7, cc = idx & 127;    // rr: s-local, cc: n-local
      int n = blockIdx.y * 128 + cc;
      int h = n >> 6, e = n & 63;
      bf16x8 vq = *(const bf16x8*)(ts + rr * 136 + cc);
      *(bf16x8*)(out + ((size_t)(b * 16 + h) * 2048 + sbase + rr) * 64 + e) = vq;
    }
  }
}

// ---------------- flash attention, S^T formulation (unchanged) ----------------
__global__ __launch_bounds__(256, 4) void attn(
    const bf16_t* __restrict__ qw, const bf16_t* __restrict__ kw,
    const bf16_t* __restrict__ vtw, bf16_t* __restrict__ att)
{
  __shared__ bf16_t k_s[64 * 64];
  __shared__ bf16_t v_s[64 * 64];
  __shared__ bf16_t qe_s[64 * 72];
  const int bh = blockIdx.x, qt = blockIdx.y;
  const int t = threadIdx.x, w = t >> 6, l = t & 63, lq = l >> 4, lr = l & 15;

  const bf16_t* qbase = qw + ((size_t)bh * 2048 + qt * 64) * 64;
  #pragma unroll
  for (int i = 0; i < 2; i++) {
    int g = t + i * 256;
    int r = g >> 3, pc = g & 7;
    int lc = pc ^ (r & 7);
    gl_lds16(qbase + (size_t)r * 64 + lc * 8, qe_s + i * 2048 + w * 512);
  }
  __syncthreads();
  bf16x8 qf[2];
  #pragma unroll
  for (int kk = 0; kk < 2; kk++) {
    int R = w * 16 + lr;
    int ch = (kk * 4 + lq) ^ (R & 7);
    qf[kk] = *(const bf16x8*)(qe_s + R * 64 + ch * 8);
  }

  f32x4 O[4];
  f32x4 zero = {0.f, 0.f, 0.f, 0.f};
  #pragma unroll
  for (int et = 0; et < 4; et++) O[et] = zero;
  float lsum = 0.f;

  for (int kt = 0; kt < 32; ++kt) {
    __syncthreads();
    const bf16_t* kbase = kw + ((size_t)bh * 2048 + kt * 64) * 64;
    const bf16_t* vbase = vtw + (size_t)bh * 131072 + (size_t)kt * 64;
    #pragma unroll
    for (int i = 0; i < 2; i++) {
      int g = t + i * 256;
      int r = g >> 3, pc = g & 7;
      int lc = pc ^ (r & 7);
      gl_lds16(kbase + (size_t)r * 64 + lc * 8, k_s + i * 2048 + w * 512);
      gl_lds16(vbase + (size_t)r * 2048 + lc * 8, v_s + i * 2048 + w * 512);
    }
    __syncthreads();

    f32x4 sc[4];
    #pragma unroll
    for (int j = 0; j < 4; j++) sc[j] = zero;
    #pragma unroll
    for (int kk = 0; kk < 2; kk++) {
      #pragma unroll
      for (int j = 0; j < 4; j++) {
        int R = j * 16 + lr;
        int ch = (kk * 4 + lq) ^ (R & 7);
        bf16x8 kf = *(const bf16x8*)(k_s + R * 64 + ch * 8);
        sc[j] = mfma16(kf, qf[kk], sc[j]);   // D[key][q]
      }
    }

    bf16x8 pb[2];
    #pragma unroll
    for (int ks2 = 0; ks2 < 2; ks2++) {
      #pragma unroll
      for (int r = 0; r < 4; r++) {
        float e0 = __expf(sc[2 * ks2][r]);
        float e1 = __expf(sc[2 * ks2 + 1][r]);
        lsum += e0 + e1;
        pb[ks2][r] = (bf16_t)e0;
        pb[ks2][4 + r] = (bf16_t)e1;
      }
    }

    #pragma unroll
    for (int ks2 = 0; ks2 < 2; ks2++) {
      #pragma unroll
      for (int et = 0; et < 4; et++) {
        int R = et * 16 + lr;
        int ch = (ks2 * 4 + lq) ^ (R & 7);
        bf16x8 vf = *(const bf16x8*)(v_s + R * 64 + ch * 8);
        O[et] = mfma16(vf, pb[ks2], O[et]);
      }
    }
  }

  float s = lsum;
  s += __shfl_xor(s, 16);
  s += __shfl_xor(s, 32);
  float rinv = 1.0f / s;

  #pragma unroll
  for (int et = 0; et < 4; et++) {
    bf16x4 pv;
    #pragma unroll
    for (int r = 0; r < 4; r++) pv[r] = (bf16_t)(O[et][r] * rinv);
    *(bf16x4*)(qe_s + (w * 16 + lr) * 72 + et * 16 + lq * 4) = pv;
  }
  __syncthreads();
  const int b = bh >> 4, h = bh & 15;
  #pragma unroll
  for (int i = 0; i < 2; i++) {
    int c = t + i * 256;
    int row = c >> 3, c8 = c & 7;
    bf16x8 vv = *(const bf16x8*)(qe_s + row * 72 + c8 * 8);
    *(bf16x8*)(att + ((size_t)b * 2048 + qt * 64 + row) * 1024 + h * 64 + c8 * 8) = vv;
  }
}

// ---------------- output projection (A bf16, W bf16, out fp32) ----------------
// 64x64 tile, grid (64, 16) -> 1024 blocks (4/CU). Both operands via LDS-DMA.
__global__ __launch_bounds__(256, 4) void gemm_out(
    const bf16_t* __restrict__ A, const bf16_t* __restrict__ W,
    const float* __restrict__ bias, float* __restrict__ out)
{
  __shared__ bf16_t a_s[64 * 64];    // 8 KB
  __shared__ bf16_t b_s[64 * 64];    // 8 KB
  const int K = 1024;
  const bf16_t* Ab = A + (size_t)blockIdx.x * 64 * K;
  const bf16_t* Wb = W + (size_t)blockIdx.y * 64 * K;
  const int t = threadIdx.x, w = t >> 6, l = t & 63, lq = l >> 4, lr = l & 15;
  const int mh = w & 1, nh = w >> 1;

  f32x4 acc[2][2];
  f32x4 zero = {0.f, 0.f, 0.f, 0.f};
  #pragma unroll
  for (int i = 0; i < 2; i++)
    #pragma unroll
    for (int j = 0; j < 2; j++) acc[i][j] = zero;

  for (int k0 = 0; k0 < K; k0 += 64) {
    __syncthreads();
    #pragma unroll
    for (int i = 0; i < 2; i++) {
      int g = t + i * 256;
      int r = g >> 3, pc = g & 7;
      int lc = pc ^ (r & 7);
      gl_lds16(Ab + (size_t)r * K + k0 + lc * 8, a_s + i * 2048 + w * 512);
      gl_lds16(Wb + (size_t)r * K + k0 + lc * 8, b_s + i * 2048 + w * 512);
    }
    __syncthreads();
    #pragma unroll
    for (int kk = 0; kk < 2; kk++) {
      bf16x8 af[2], bfr[2];
      #pragma unroll
      for (int i = 0; i < 2; i++) {
        int R = mh * 32 + i * 16 + lr;
        int ch = (kk * 4 + lq) ^ (R & 7);
        af[i] = *(const bf16x8*)(a_s + R * 64 + ch * 8);
      }
      #pragma unroll
      for (int j = 0; j < 2; j++) {
        int R = nh * 32 + j * 16 + lr;
        int ch = (kk * 4 + lq) ^ (R & 7);
        bfr[j] = *(const bf16x8*)(b_s + R * 64 + ch * 8);
      }
      #pragma unroll
      for (int i = 0; i < 2; i++)
        #pragma unroll
        for (int j = 0; j < 2; j++)
          acc[i][j] = mfma16(af[i], bfr[j], acc[i][j]);
    }
  }

  #pragma unroll
  for (int i = 0; i < 2; i++) {
    #pragma unroll
    for (int j = 0; j < 2; j++) {
      int col = blockIdx.y * 64 + nh * 32 + j * 16 + lr;
      float bz = bias[col];
      #pragma unroll
      for (int r = 0; r < 4; r++) {
        int row = blockIdx.x * 64 + mh * 32 + i * 16 + lq * 4 + r;
        out[(size_t)row * 1024 + col] = acc[i][j][r] + bz;
      }
    }
  }
}

// ---------------- launch ----------------
extern "C" void kernel_launch(void* const* d_in, const int* in_sizes, int n_in,
                              void* d_out, int out_size, void* d_ws, size_t ws_size,
                              hipStream_t stream) {
  (void)in_sizes; (void)n_in; (void)out_size;
  const float* V  = (const float*)d_in[0];
  const float* Kx = (const float*)d_in[1];
  const float* Q  = (const float*)d_in[2];
  const float* Wv = (const float*)d_in[3];
  const float* bv = (const float*)d_in[4];
  const float* Wk = (const float*)d_in[5];
  const float* bk = (const float*)d_in[6];
  const float* Wq = (const float*)d_in[7];
  const float* bq = (const float*)d_in[8];
  const float* Wo = (const float*)d_in[9];
  const float* bo = (const float*)d_in[10];

  const size_t E = 1048576;
  if (ws_size < 20 * E * sizeof(bf16_t)) return;  // 40 MB needed

  bf16_t* ws = (bf16_t*)d_ws;
  bf16_t* cWo   = ws;            // 1E
  bf16_t* cWv   = ws + E;        // 1E
  bf16_t* cWk   = ws + 2 * E;    // 1E
  bf16_t* cWq   = ws + 3 * E;    // 1E
  bf16_t* q_ws  = ws + 4 * E;    // 4E  [bh][s][e], pre-scaled by 0.125
  bf16_t* k_ws  = ws + 8 * E;    // 4E  [bh][s][e]
  bf16_t* vt_ws = ws + 12 * E;   // 4E  [bh][e][s_perm]
  bf16_t* att_ws= ws + 16 * E;   // 4E  [b][s][h*64+e]

  CvtWArgs cw;
  cw.src[0] = Wo; cw.src[1] = Wv; cw.src[2] = Wk; cw.src[3] = Wq;
  convert_w<<<2048, 256, 0, stream>>>(cw, ws);

  ProjArgs pa;
  pa.A[0] = V;   pa.A[1] = Kx;  pa.A[2] = Q;
  pa.W[0] = cWv; pa.W[1] = cWk; pa.W[2] = cWq;
  pa.bias[0] = bv; pa.bias[1] = bk; pa.bias[2] = bq;
  pa.out[0] = vt_ws; pa.out[1] = k_ws; pa.out[2] = q_ws;
  pa.scale[0] = 1.f; pa.scale[1] = 1.f; pa.scale[2] = 0.125f;
  gemm_proj<<<dim3(64, 8, 3), 256, 0, stream>>>(pa);

  attn<<<dim3(32, 32), 256, 0, stream>>>(q_ws, k_ws, vt_ws, att_ws);

  gemm_out<<<dim3(64, 16), 256, 0, stream>>>(att_ws, cWo, bo, (float*)d_out);
}